// Round 4
// baseline (489.416 us; speedup 1.0000x reference)
//
#include <hip/hip_runtime.h>

// ---------------------------------------------------------------------------
// TasteGNN (fp32 storage, bf16-quantized values):
//   h_ing = x_ing@W_ing+b; GAT edge softmax over dst segments; weighted
//   scatter-agg; relu; (semantic attn over 1 metapath == 1.0, skipped);
//   residual blend 0.5/0.5. out_ing = x_ing passthrough.
//
// KEY HARNESS FACT (forensics rounds 0-3): float tensors are FP32 in memory
// (reference dtype float32), values bf16-quantized. Outputs fp32 too.
//
// Memory plan (all inside d_out, no d_ws dependence):
//   bytes [0, 25.6MB)      : h_ing staged as bf16 (ushort), read by k_agg
//   bytes [26MB, ~30MB)    : scratch (a_src, a_dst, CSR arrays, Wt, u, v)
//   bytes [51.2MB, 76.8MB) : out_taste (fp32, final output region 1)
//   final op: copy fp32 x_ing over bytes [0, 51.2MB) (output region 0)
// ---------------------------------------------------------------------------

typedef __attribute__((ext_vector_type(8))) short short8;   // 8 x bf16
typedef __attribute__((ext_vector_type(4))) float f32x4;

__device__ __forceinline__ float b2f(unsigned short u) {
    return __uint_as_float(((unsigned int)u) << 16);
}
__device__ __forceinline__ unsigned short f2b(float f) {
    unsigned int x = __float_as_uint(f);
    x += 0x7fffu + ((x >> 16) & 1u);   // RNE; exact for bf16-quantized values
    return (unsigned short)(x >> 16);
}

#define D 128

// --- prep: Wt=bf16(W_ing^T); u=W_ing@att_src; v=W_taste@att_dst; consts ----
__global__ __launch_bounds__(256) void k_prep(
        const float* __restrict__ W_ing,  const float* __restrict__ b_ing,
        const float* __restrict__ W_taste,const float* __restrict__ b_taste,
        const float* __restrict__ att_src,const float* __restrict__ att_dst,
        unsigned short* __restrict__ Wt,
        float* __restrict__ u, float* __restrict__ v, float* __restrict__ cvals)
{
    int tid = threadIdx.x;
    for (int i = 0; i < 64; ++i) {                 // transpose + bf16-convert
        int idx = i * 256 + tid;
        int k = idx >> 7, j = idx & 127;
        Wt[j * D + k] = f2b(W_ing[idx]);
    }
    if (tid < 128) {
        float s = 0.f;
        for (int j = 0; j < D; ++j) s += W_ing[tid * D + j] * att_src[j];
        u[tid] = s;
    } else {
        int k = tid - 128;
        float s = 0.f;
        for (int j = 0; j < D; ++j) s += W_taste[k * D + j] * att_dst[j];
        v[k] = s;
    }
    if (tid == 0) {
        float s = 0.f;
        for (int j = 0; j < D; ++j) s += b_ing[j] * att_src[j];
        cvals[0] = s;
    }
    if (tid == 1) {
        float s = 0.f;
        for (int j = 0; j < D; ++j) s += b_taste[j] * att_dst[j];
        cvals[1] = s;
    }
}

// --- histogram of dst ------------------------------------------------------
__global__ __launch_bounds__(256) void k_hist(const int* __restrict__ dst,
                                              int* __restrict__ counts, int E)
{
    int e = blockIdx.x * 256 + threadIdx.x;
    if (e < E) atomicAdd(&counts[dst[e]], 1);
}

// --- exclusive scan of counts -> offsets[n+1], cursor copy (1 block) -------
__global__ __launch_bounds__(1024) void k_scan(const int* __restrict__ counts,
                                               int* __restrict__ offsets,
                                               int* __restrict__ cursor, int n)
{
    __shared__ int part[1024];
    int tid = threadIdx.x;
    int chunk = (n + 1023) / 1024;
    int b = tid * chunk;
    int s = 0;
    for (int i = 0; i < chunk; ++i)
        if (b + i < n) s += counts[b + i];
    part[tid] = s;
    __syncthreads();
    for (int off = 1; off < 1024; off <<= 1) {
        int val = (tid >= off) ? part[tid - off] : 0;
        __syncthreads();
        part[tid] += val;
        __syncthreads();
    }
    int base = part[tid] - s;  // exclusive prefix
    int running = base;
    for (int i = 0; i < chunk; ++i) {
        if (b + i < n) {
            offsets[b + i] = running;
            cursor[b + i] = running;
            running += counts[b + i];
        }
    }
    if (tid == 1023) offsets[n] = part[1023];
}

// --- scatter: src indices sorted by dst ------------------------------------
__global__ __launch_bounds__(256) void k_scatter(const int* __restrict__ dst,
                                                 const int* __restrict__ srcix,
                                                 int* __restrict__ cursor,
                                                 int* __restrict__ src_sorted, int E)
{
    int e = blockIdx.x * 256 + threadIdx.x;
    if (e < E) {
        int d = dst[e];
        int pos = atomicAdd(&cursor[d], 1);
        src_sorted[pos] = srcix[e];
    }
}

// --- GEMM: H(bf16) = X(fp32) @ W + b, bf16 MFMA 16x16x32 -------------------
// block = 4 waves; wave: 32 rows x 128 cols (2 m-tiles x 8 n-tiles)
__global__ __launch_bounds__(256) void k_gemm(const float* __restrict__ X,
                                              const unsigned short* __restrict__ Wt,
                                              const float* __restrict__ bvec,
                                              unsigned short* __restrict__ H, int M)
{
    int wave = threadIdx.x >> 6;
    int lane = threadIdx.x & 63;
    int q = lane >> 4;       // quad
    int t = lane & 15;
    long mbase = (long)blockIdx.x * 128 + wave * 32;

    f32x4 acc[2][8];
    for (int i = 0; i < 2; ++i)
        for (int j = 0; j < 8; ++j)
            acc[i][j] = (f32x4){0.f, 0.f, 0.f, 0.f};

    long r0 = mbase + t;      if (r0 >= M) r0 = M - 1;
    long r1 = mbase + 16 + t; if (r1 >= M) r1 = M - 1;
    const float* A0 = X + r0 * D;
    const float* A1 = X + r1 * D;

    for (int ks = 0; ks < 4; ++ks) {
        int ko = ks * 32 + q * 8;
        float4 f0a = *(const float4*)(A0 + ko);
        float4 f0b = *(const float4*)(A0 + ko + 4);
        float4 f1a = *(const float4*)(A1 + ko);
        float4 f1b = *(const float4*)(A1 + ko + 4);
        short8 a0, a1;
        a0[0]=f2b(f0a.x); a0[1]=f2b(f0a.y); a0[2]=f2b(f0a.z); a0[3]=f2b(f0a.w);
        a0[4]=f2b(f0b.x); a0[5]=f2b(f0b.y); a0[6]=f2b(f0b.z); a0[7]=f2b(f0b.w);
        a1[0]=f2b(f1a.x); a1[1]=f2b(f1a.y); a1[2]=f2b(f1a.z); a1[3]=f2b(f1a.w);
        a1[4]=f2b(f1b.x); a1[5]=f2b(f1b.y); a1[6]=f2b(f1b.z); a1[7]=f2b(f1b.w);
#pragma unroll
        for (int nt = 0; nt < 8; ++nt) {
            short8 bfr = *(const short8*)(Wt + (nt * 16 + t) * D + ko);
            acc[0][nt] = __builtin_amdgcn_mfma_f32_16x16x32_bf16(a0, bfr, acc[0][nt], 0, 0, 0);
            acc[1][nt] = __builtin_amdgcn_mfma_f32_16x16x32_bf16(a1, bfr, acc[1][nt], 0, 0, 0);
        }
    }
    // C/D: col(n) = lane&15, row(m) = quad*4 + reg   [verified m89/m91]
#pragma unroll
    for (int mt = 0; mt < 2; ++mt) {
#pragma unroll
        for (int r = 0; r < 4; ++r) {
            long row = mbase + mt * 16 + q * 4 + r;
            if (row < M) {
#pragma unroll
                for (int nt = 0; nt < 8; ++nt) {
                    H[row * D + nt * 16 + t] = f2b(acc[mt][nt][r] + bvec[nt * 16 + t]);
                }
            }
        }
    }
}

// --- row dot: out[i] = x[i,:].w + c  (wave = 4 rows, 16 lanes/row) ---------
__global__ __launch_bounds__(256) void k_rowdot(const float* __restrict__ X,
                                                const float* __restrict__ w,
                                                const float* __restrict__ cptr,
                                                float* __restrict__ out, int M)
{
    int gw = (blockIdx.x * 256 + threadIdx.x) >> 6;
    int lane = threadIdx.x & 63;
    long row = (long)gw * 4 + (lane >> 4);
    int k = (lane & 15) * 8;
    float s = 0.f;
    if (row < M) {
        float4 a = *(const float4*)(X + row * D + k);
        float4 b = *(const float4*)(X + row * D + k + 4);
        s = a.x * w[k]     + a.y * w[k + 1] + a.z * w[k + 2] + a.w * w[k + 3]
          + b.x * w[k + 4] + b.y * w[k + 5] + b.z * w[k + 6] + b.w * w[k + 7];
    }
    s += __shfl_xor(s, 1);
    s += __shfl_xor(s, 2);
    s += __shfl_xor(s, 4);
    s += __shfl_xor(s, 8);
    if ((lane & 15) == 0 && row < M) out[row] = s + cptr[0];
}

// --- per-dst: segment softmax + weighted agg + relu + residual -------------
// one wave per dst node; lane holds 2 cols (h as bf16 pair, x/out as fp32)
__global__ __launch_bounds__(256) void k_agg(const int* __restrict__ offsets,
                                             const int* __restrict__ src_sorted,
                                             const float* __restrict__ a_src,
                                             const float* __restrict__ a_dst,
                                             const unsigned short* __restrict__ H,
                                             const float* __restrict__ x_taste,
                                             float* __restrict__ out_taste,
                                             int Nt)
{
    int d = (blockIdx.x * 256 + threadIdx.x) >> 6;
    int lane = threadIdx.x & 63;
    if (d >= Nt) return;
    int start = offsets[d], end = offsets[d + 1];
    float ad = a_dst[d];

    // segment max of leaky_relu(a_src+a_dst)
    float m = -3.4e38f;
    for (int base = start; base < end; base += 64) {
        int e = base + lane;
        if (e < end) {
            float l = a_src[src_sorted[e]] + ad;
            l = l > 0.f ? l : 0.2f * l;
            m = fmaxf(m, l);
        }
    }
#pragma unroll
    for (int off = 32; off; off >>= 1) m = fmaxf(m, __shfl_xor(m, off));

    // segment sum of exp
    float ssum = 0.f;
    for (int base = start; base < end; base += 64) {
        int e = base + lane;
        if (e < end) {
            float l = a_src[src_sorted[e]] + ad;
            l = l > 0.f ? l : 0.2f * l;
            ssum += __expf(l - m);
        }
    }
#pragma unroll
    for (int off = 32; off; off >>= 1) ssum += __shfl_xor(ssum, off);
    float inv = 1.0f / (ssum + 1e-16f);

    // weighted aggregation of h_ing rows (bf16-packed, 4B/lane = 2 cols)
    float acc0 = 0.f, acc1 = 0.f;
    for (int e = start; e < end; ++e) {
        int s = src_sorted[e];                       // wave-broadcast load
        float l = a_src[s] + ad;
        l = l > 0.f ? l : 0.2f * l;
        float wgt = __expf(l - m) * inv;
        unsigned int hv = *(const unsigned int*)(H + (long)s * D + lane * 2);
        acc0 += wgt * b2f((unsigned short)(hv & 0xffffu));
        acc1 += wgt * b2f((unsigned short)(hv >> 16));
    }

    float2 xv = *(const float2*)(x_taste + (long)d * D + lane * 2);
    float2 ov;
    ov.x = 0.5f * (fmaxf(acc0, 0.f) + xv.x);
    ov.y = 0.5f * (fmaxf(acc1, 0.f) + xv.y);
    *(float2*)(out_taste + (long)d * D + lane * 2) = ov;
}

// --- passthrough copy: out_ing = x_ing (16B/thread, grid-stride) -----------
__global__ __launch_bounds__(256) void k_copy(const uint4* __restrict__ src,
                                              uint4* __restrict__ dst, long n16)
{
    long i = (long)blockIdx.x * 256 + threadIdx.x;
    long stride = (long)gridDim.x * 256;
    for (; i < n16; i += stride) dst[i] = src[i];
}

extern "C" void kernel_launch(void* const* d_in, const int* in_sizes, int n_in,
                              void* d_out, int out_size, void* d_ws, size_t ws_size,
                              hipStream_t stream)
{
    const float* x_ing   = (const float*)d_in[0];
    const float* x_taste = (const float*)d_in[1];
    const float* W_ing   = (const float*)d_in[2];
    const float* b_ing   = (const float*)d_in[3];
    const float* W_taste = (const float*)d_in[4];
    const float* b_taste = (const float*)d_in[5];
    const float* att_src = (const float*)d_in[6];
    const float* att_dst = (const float*)d_in[7];
    // d_in[8..10] = Wk, bk, q: dead (softmax over single metapath == 1.0)
    const int* src_idx = (const int*)d_in[11];
    const int* dst_idx = (const int*)d_in[12];

    const int NI = in_sizes[0] / D;   // 100000
    const int NT = in_sizes[1] / D;   // 50000
    const int E  = in_sizes[11];      // 600000

    float* out = (float*)d_out;
    float* out_taste = out + (size_t)NI * D;               // region 1 (fp32)
    unsigned short* h_ing = (unsigned short*)d_out;        // bytes [0,25.6MB)

    // scratch inside d_out at byte offset 26MB (region 0 is 51.2MB; this span
    // is wiped by the final x_ing copy) — no dependence on ws_size
    char* ws = (char*)d_out + (size_t)26 * 1024 * 1024;
    size_t off = 0;
    auto alloc = [&](size_t bytes) -> void* {
        void* p = ws + off;
        off = (off + bytes + 255) & ~(size_t)255;
        return p;
    };
    float* a_src     = (float*)alloc((size_t)NI * 4);
    float* a_dst     = (float*)alloc((size_t)NT * 4);
    int* counts      = (int*)alloc((size_t)NT * 4);
    int* cursor      = (int*)alloc((size_t)NT * 4);
    int* offsets     = (int*)alloc((size_t)(NT + 1) * 4);
    int* src_sorted  = (int*)alloc((size_t)E * 4);
    unsigned short* Wt = (unsigned short*)alloc((size_t)D * D * 2);
    float* u         = (float*)alloc(D * 4);
    float* v         = (float*)alloc(D * 4);
    float* cvals     = (float*)alloc(2 * 4);
    (void)d_ws; (void)ws_size;

    hipMemsetAsync(counts, 0, (size_t)NT * 4, stream);

    k_prep<<<1, 256, 0, stream>>>(W_ing, b_ing, W_taste, b_taste,
                                  att_src, att_dst, Wt, u, v, cvals);

    k_hist<<<(E + 255) / 256, 256, 0, stream>>>(dst_idx, counts, E);
    k_scan<<<1, 1024, 0, stream>>>(counts, offsets, cursor, NT);
    k_scatter<<<(E + 255) / 256, 256, 0, stream>>>(dst_idx, src_idx, cursor, src_sorted, E);

    k_gemm<<<(NI + 127) / 128, 256, 0, stream>>>(x_ing, Wt, b_ing, h_ing, NI);

    // a_src = x_ing @ (W_ing @ att_src) + b_ing.att_src   (linearity)
    k_rowdot<<<((NI + 3) / 4 * 64 + 255) / 256, 256, 0, stream>>>(x_ing, u, cvals + 0, a_src, NI);
    // a_dst = x_taste @ (W_taste @ att_dst) + b_taste.att_dst
    k_rowdot<<<((NT + 3) / 4 * 64 + 255) / 256, 256, 0, stream>>>(x_taste, v, cvals + 1, a_dst, NT);

    k_agg<<<(NT * 64 + 255) / 256, 256, 0, stream>>>(offsets, src_sorted, a_src, a_dst,
                                                     h_ing, x_taste, out_taste, NT);

    // out_ing = x_ing passthrough — LAST op, wipes h_ing staging + scratch
    long n16 = ((long)NI * D * 4) / 16;
    k_copy<<<2048, 256, 0, stream>>>((const uint4*)x_ing, (uint4*)out, n16);
}

// Round 5
// 381.034 us; speedup vs baseline: 1.2844x; 1.2844x over previous
//
#include <hip/hip_runtime.h>

// ---------------------------------------------------------------------------
// TasteGNN (fp32 storage, bf16-quantized values):
//   h_ing = x_ing@W_ing+b; GAT edge softmax over dst segments; weighted
//   scatter-agg; relu; (semantic attn over 1 metapath == 1.0, skipped);
//   residual blend 0.5/0.5. out_ing = x_ing passthrough.
//
// HARNESS FACT (r0-3 forensics): float tensors are FP32 in memory.
// R4: passed, 489us. k_scan (1-block serial scan) was 128us / 26% -> replaced
// with 3-phase multi-block scan (~10us total).
//
// Memory plan (all inside d_out, no d_ws dependence):
//   bytes [0, 25.6MB)      : h_ing staged as bf16 (ushort), read by k_agg
//   bytes [26MB, ~30MB)    : scratch (a_src, a_dst, CSR arrays, Wt, u, v)
//   bytes [51.2MB, 76.8MB) : out_taste (fp32, final output region 1)
//   final op: copy fp32 x_ing over bytes [0, 51.2MB) (output region 0)
// ---------------------------------------------------------------------------

typedef __attribute__((ext_vector_type(8))) short short8;   // 8 x bf16
typedef __attribute__((ext_vector_type(4))) float f32x4;

__device__ __forceinline__ float b2f(unsigned short u) {
    return __uint_as_float(((unsigned int)u) << 16);
}
__device__ __forceinline__ unsigned short f2b(float f) {
    unsigned int x = __float_as_uint(f);
    x += 0x7fffu + ((x >> 16) & 1u);   // RNE; exact for bf16-quantized values
    return (unsigned short)(x >> 16);
}

#define D 128

// --- prep: Wt=bf16(W_ing^T); u=W_ing@att_src; v=W_taste@att_dst; consts ----
__global__ __launch_bounds__(256) void k_prep(
        const float* __restrict__ W_ing,  const float* __restrict__ b_ing,
        const float* __restrict__ W_taste,const float* __restrict__ b_taste,
        const float* __restrict__ att_src,const float* __restrict__ att_dst,
        unsigned short* __restrict__ Wt,
        float* __restrict__ u, float* __restrict__ v, float* __restrict__ cvals)
{
    int tid = threadIdx.x;
    for (int i = 0; i < 64; ++i) {                 // transpose + bf16-convert
        int idx = i * 256 + tid;
        int k = idx >> 7, j = idx & 127;
        Wt[j * D + k] = f2b(W_ing[idx]);
    }
    if (tid < 128) {
        float s = 0.f;
        for (int j = 0; j < D; ++j) s += W_ing[tid * D + j] * att_src[j];
        u[tid] = s;
    } else {
        int k = tid - 128;
        float s = 0.f;
        for (int j = 0; j < D; ++j) s += W_taste[k * D + j] * att_dst[j];
        v[k] = s;
    }
    if (tid == 0) {
        float s = 0.f;
        for (int j = 0; j < D; ++j) s += b_ing[j] * att_src[j];
        cvals[0] = s;
    }
    if (tid == 1) {
        float s = 0.f;
        for (int j = 0; j < D; ++j) s += b_taste[j] * att_dst[j];
        cvals[1] = s;
    }
}

// --- histogram of dst ------------------------------------------------------
__global__ __launch_bounds__(256) void k_hist(const int* __restrict__ dst,
                                              int* __restrict__ counts, int E)
{
    int e = blockIdx.x * 256 + threadIdx.x;
    if (e < E) atomicAdd(&counts[dst[e]], 1);
}

// --- 3-phase scan: A) per-block sums  B) scan sums  C) block scan + prefix -
__global__ __launch_bounds__(256) void k_scanA(const int* __restrict__ counts,
                                               int* __restrict__ blocksums, int n)
{
    __shared__ int lds[256];
    int tid = threadIdx.x;
    int i = blockIdx.x * 256 + tid;
    lds[tid] = (i < n) ? counts[i] : 0;
    __syncthreads();
#pragma unroll
    for (int off = 128; off > 0; off >>= 1) {
        if (tid < off) lds[tid] += lds[tid + off];
        __syncthreads();
    }
    if (tid == 0) blocksums[blockIdx.x] = lds[0];
}

__global__ __launch_bounds__(256) void k_scanB(const int* __restrict__ blocksums,
                                               int* __restrict__ blockpre,
                                               int* __restrict__ offsets,
                                               int nb, int n)
{
    __shared__ int lds[256];
    int tid = threadIdx.x;
    int v = (tid < nb) ? blocksums[tid] : 0;
    lds[tid] = v;
    __syncthreads();
#pragma unroll
    for (int off = 1; off < 256; off <<= 1) {
        int t = (tid >= off) ? lds[tid - off] : 0;
        __syncthreads();
        lds[tid] += t;
        __syncthreads();
    }
    if (tid < nb) blockpre[tid] = lds[tid] - v;   // exclusive prefix
    if (tid == 255) offsets[n] = lds[255];        // total (tail zeros)
}

__global__ __launch_bounds__(256) void k_scanC(const int* __restrict__ counts,
                                               const int* __restrict__ blockpre,
                                               int* __restrict__ offsets,
                                               int* __restrict__ cursor, int n)
{
    __shared__ int lds[256];
    int tid = threadIdx.x;
    int i = blockIdx.x * 256 + tid;
    int v = (i < n) ? counts[i] : 0;
    lds[tid] = v;
    __syncthreads();
#pragma unroll
    for (int off = 1; off < 256; off <<= 1) {
        int t = (tid >= off) ? lds[tid - off] : 0;
        __syncthreads();
        lds[tid] += t;
        __syncthreads();
    }
    if (i < n) {
        int o = blockpre[blockIdx.x] + lds[tid] - v;   // exclusive
        offsets[i] = o;
        cursor[i] = o;
    }
}

// --- scatter: src indices sorted by dst ------------------------------------
__global__ __launch_bounds__(256) void k_scatter(const int* __restrict__ dst,
                                                 const int* __restrict__ srcix,
                                                 int* __restrict__ cursor,
                                                 int* __restrict__ src_sorted, int E)
{
    int e = blockIdx.x * 256 + threadIdx.x;
    if (e < E) {
        int d = dst[e];
        int pos = atomicAdd(&cursor[d], 1);
        src_sorted[pos] = srcix[e];
    }
}

// --- GEMM: H(bf16) = X(fp32) @ W + b, bf16 MFMA 16x16x32 -------------------
// block = 4 waves; wave: 32 rows x 128 cols (2 m-tiles x 8 n-tiles)
__global__ __launch_bounds__(256) void k_gemm(const float* __restrict__ X,
                                              const unsigned short* __restrict__ Wt,
                                              const float* __restrict__ bvec,
                                              unsigned short* __restrict__ H, int M)
{
    int wave = threadIdx.x >> 6;
    int lane = threadIdx.x & 63;
    int q = lane >> 4;       // quad
    int t = lane & 15;
    long mbase = (long)blockIdx.x * 128 + wave * 32;

    f32x4 acc[2][8];
    for (int i = 0; i < 2; ++i)
        for (int j = 0; j < 8; ++j)
            acc[i][j] = (f32x4){0.f, 0.f, 0.f, 0.f};

    long r0 = mbase + t;      if (r0 >= M) r0 = M - 1;
    long r1 = mbase + 16 + t; if (r1 >= M) r1 = M - 1;
    const float* A0 = X + r0 * D;
    const float* A1 = X + r1 * D;

    for (int ks = 0; ks < 4; ++ks) {
        int ko = ks * 32 + q * 8;
        float4 f0a = *(const float4*)(A0 + ko);
        float4 f0b = *(const float4*)(A0 + ko + 4);
        float4 f1a = *(const float4*)(A1 + ko);
        float4 f1b = *(const float4*)(A1 + ko + 4);
        short8 a0, a1;
        a0[0]=f2b(f0a.x); a0[1]=f2b(f0a.y); a0[2]=f2b(f0a.z); a0[3]=f2b(f0a.w);
        a0[4]=f2b(f0b.x); a0[5]=f2b(f0b.y); a0[6]=f2b(f0b.z); a0[7]=f2b(f0b.w);
        a1[0]=f2b(f1a.x); a1[1]=f2b(f1a.y); a1[2]=f2b(f1a.z); a1[3]=f2b(f1a.w);
        a1[4]=f2b(f1b.x); a1[5]=f2b(f1b.y); a1[6]=f2b(f1b.z); a1[7]=f2b(f1b.w);
#pragma unroll
        for (int nt = 0; nt < 8; ++nt) {
            short8 bfr = *(const short8*)(Wt + (nt * 16 + t) * D + ko);
            acc[0][nt] = __builtin_amdgcn_mfma_f32_16x16x32_bf16(a0, bfr, acc[0][nt], 0, 0, 0);
            acc[1][nt] = __builtin_amdgcn_mfma_f32_16x16x32_bf16(a1, bfr, acc[1][nt], 0, 0, 0);
        }
    }
    // C/D: col(n) = lane&15, row(m) = quad*4 + reg   [verified m89/m91]
#pragma unroll
    for (int mt = 0; mt < 2; ++mt) {
#pragma unroll
        for (int r = 0; r < 4; ++r) {
            long row = mbase + mt * 16 + q * 4 + r;
            if (row < M) {
#pragma unroll
                for (int nt = 0; nt < 8; ++nt) {
                    H[row * D + nt * 16 + t] = f2b(acc[mt][nt][r] + bvec[nt * 16 + t]);
                }
            }
        }
    }
}

// --- row dot: out[i] = x[i,:].w + c  (wave = 4 rows, 16 lanes/row) ---------
__global__ __launch_bounds__(256) void k_rowdot(const float* __restrict__ X,
                                                const float* __restrict__ w,
                                                const float* __restrict__ cptr,
                                                float* __restrict__ out, int M)
{
    int gw = (blockIdx.x * 256 + threadIdx.x) >> 6;
    int lane = threadIdx.x & 63;
    long row = (long)gw * 4 + (lane >> 4);
    int k = (lane & 15) * 8;
    float s = 0.f;
    if (row < M) {
        float4 a = *(const float4*)(X + row * D + k);
        float4 b = *(const float4*)(X + row * D + k + 4);
        s = a.x * w[k]     + a.y * w[k + 1] + a.z * w[k + 2] + a.w * w[k + 3]
          + b.x * w[k + 4] + b.y * w[k + 5] + b.z * w[k + 6] + b.w * w[k + 7];
    }
    s += __shfl_xor(s, 1);
    s += __shfl_xor(s, 2);
    s += __shfl_xor(s, 4);
    s += __shfl_xor(s, 8);
    if ((lane & 15) == 0 && row < M) out[row] = s + cptr[0];
}

// --- per-dst: segment softmax + weighted agg + relu + residual -------------
// one wave per dst node; lane holds 2 cols (h as bf16 pair, x/out as fp32)
__global__ __launch_bounds__(256) void k_agg(const int* __restrict__ offsets,
                                             const int* __restrict__ src_sorted,
                                             const float* __restrict__ a_src,
                                             const float* __restrict__ a_dst,
                                             const unsigned short* __restrict__ H,
                                             const float* __restrict__ x_taste,
                                             float* __restrict__ out_taste,
                                             int Nt)
{
    int d = (blockIdx.x * 256 + threadIdx.x) >> 6;
    int lane = threadIdx.x & 63;
    if (d >= Nt) return;
    int start = offsets[d], end = offsets[d + 1];
    float ad = a_dst[d];

    // segment max of leaky_relu(a_src+a_dst)
    float m = -3.4e38f;
    for (int base = start; base < end; base += 64) {
        int e = base + lane;
        if (e < end) {
            float l = a_src[src_sorted[e]] + ad;
            l = l > 0.f ? l : 0.2f * l;
            m = fmaxf(m, l);
        }
    }
#pragma unroll
    for (int off = 32; off; off >>= 1) m = fmaxf(m, __shfl_xor(m, off));

    // segment sum of exp
    float ssum = 0.f;
    for (int base = start; base < end; base += 64) {
        int e = base + lane;
        if (e < end) {
            float l = a_src[src_sorted[e]] + ad;
            l = l > 0.f ? l : 0.2f * l;
            ssum += __expf(l - m);
        }
    }
#pragma unroll
    for (int off = 32; off; off >>= 1) ssum += __shfl_xor(ssum, off);
    float inv = 1.0f / (ssum + 1e-16f);

    // weighted aggregation of h_ing rows (bf16-packed, 4B/lane = 2 cols)
    float acc0 = 0.f, acc1 = 0.f;
    for (int e = start; e < end; ++e) {
        int s = src_sorted[e];                       // wave-broadcast load
        float l = a_src[s] + ad;
        l = l > 0.f ? l : 0.2f * l;
        float wgt = __expf(l - m) * inv;
        unsigned int hv = *(const unsigned int*)(H + (long)s * D + lane * 2);
        acc0 += wgt * b2f((unsigned short)(hv & 0xffffu));
        acc1 += wgt * b2f((unsigned short)(hv >> 16));
    }

    float2 xv = *(const float2*)(x_taste + (long)d * D + lane * 2);
    float2 ov;
    ov.x = 0.5f * (fmaxf(acc0, 0.f) + xv.x);
    ov.y = 0.5f * (fmaxf(acc1, 0.f) + xv.y);
    *(float2*)(out_taste + (long)d * D + lane * 2) = ov;
}

// --- passthrough copy: out_ing = x_ing (16B/thread, grid-stride) -----------
__global__ __launch_bounds__(256) void k_copy(const uint4* __restrict__ src,
                                              uint4* __restrict__ dst, long n16)
{
    long i = (long)blockIdx.x * 256 + threadIdx.x;
    long stride = (long)gridDim.x * 256;
    for (; i < n16; i += stride) dst[i] = src[i];
}

extern "C" void kernel_launch(void* const* d_in, const int* in_sizes, int n_in,
                              void* d_out, int out_size, void* d_ws, size_t ws_size,
                              hipStream_t stream)
{
    const float* x_ing   = (const float*)d_in[0];
    const float* x_taste = (const float*)d_in[1];
    const float* W_ing   = (const float*)d_in[2];
    const float* b_ing   = (const float*)d_in[3];
    const float* W_taste = (const float*)d_in[4];
    const float* b_taste = (const float*)d_in[5];
    const float* att_src = (const float*)d_in[6];
    const float* att_dst = (const float*)d_in[7];
    // d_in[8..10] = Wk, bk, q: dead (softmax over single metapath == 1.0)
    const int* src_idx = (const int*)d_in[11];
    const int* dst_idx = (const int*)d_in[12];

    const int NI = in_sizes[0] / D;   // 100000
    const int NT = in_sizes[1] / D;   // 50000
    const int E  = in_sizes[11];      // 600000

    float* out = (float*)d_out;
    float* out_taste = out + (size_t)NI * D;               // region 1 (fp32)
    unsigned short* h_ing = (unsigned short*)d_out;        // bytes [0,25.6MB)

    // scratch inside d_out at byte offset 26MB (region 0 is 51.2MB; this span
    // is wiped by the final x_ing copy) — no dependence on ws_size
    char* ws = (char*)d_out + (size_t)26 * 1024 * 1024;
    size_t off = 0;
    auto alloc = [&](size_t bytes) -> void* {
        void* p = ws + off;
        off = (off + bytes + 255) & ~(size_t)255;
        return p;
    };
    float* a_src     = (float*)alloc((size_t)NI * 4);
    float* a_dst     = (float*)alloc((size_t)NT * 4);
    int* counts      = (int*)alloc((size_t)NT * 4);
    int* cursor      = (int*)alloc((size_t)NT * 4);
    int* offsets     = (int*)alloc((size_t)(NT + 1) * 4);
    int* src_sorted  = (int*)alloc((size_t)E * 4);
    unsigned short* Wt = (unsigned short*)alloc((size_t)D * D * 2);
    float* u         = (float*)alloc(D * 4);
    float* v         = (float*)alloc(D * 4);
    float* cvals     = (float*)alloc(2 * 4);
    int* blocksums   = (int*)alloc(256 * 4);
    int* blockpre    = (int*)alloc(256 * 4);
    (void)d_ws; (void)ws_size;

    const int nb = (NT + 255) / 256;   // 196 scan blocks

    hipMemsetAsync(counts, 0, (size_t)NT * 4, stream);

    k_prep<<<1, 256, 0, stream>>>(W_ing, b_ing, W_taste, b_taste,
                                  att_src, att_dst, Wt, u, v, cvals);

    k_hist<<<(E + 255) / 256, 256, 0, stream>>>(dst_idx, counts, E);
    k_scanA<<<nb, 256, 0, stream>>>(counts, blocksums, NT);
    k_scanB<<<1, 256, 0, stream>>>(blocksums, blockpre, offsets, nb, NT);
    k_scanC<<<nb, 256, 0, stream>>>(counts, blockpre, offsets, cursor, NT);
    k_scatter<<<(E + 255) / 256, 256, 0, stream>>>(dst_idx, src_idx, cursor, src_sorted, E);

    k_gemm<<<(NI + 127) / 128, 256, 0, stream>>>(x_ing, Wt, b_ing, h_ing, NI);

    // a_src = x_ing @ (W_ing @ att_src) + b_ing.att_src   (linearity)
    k_rowdot<<<((NI + 3) / 4 * 64 + 255) / 256, 256, 0, stream>>>(x_ing, u, cvals + 0, a_src, NI);
    // a_dst = x_taste @ (W_taste @ att_dst) + b_taste.att_dst
    k_rowdot<<<((NT + 3) / 4 * 64 + 255) / 256, 256, 0, stream>>>(x_taste, v, cvals + 1, a_dst, NT);

    k_agg<<<(NT * 64 + 255) / 256, 256, 0, stream>>>(offsets, src_sorted, a_src, a_dst,
                                                     h_ing, x_taste, out_taste, NT);

    // out_ing = x_ing passthrough — LAST op, wipes h_ing staging + scratch
    long n16 = ((long)NI * D * 4) / 16;
    k_copy<<<2048, 256, 0, stream>>>((const uint4*)x_ing, (uint4*)out, n16);
}

// Round 6
// 294.152 us; speedup vs baseline: 1.6638x; 1.2954x over previous
//
#include <hip/hip_runtime.h>

// ---------------------------------------------------------------------------
// TasteGNN (fp32 storage, bf16-quantized values):
//   h_ing = x_ing@W_ing+b; GAT edge softmax over dst segments; weighted
//   scatter-agg; relu; (semantic attn over 1 metapath == 1.0, skipped);
//   residual blend 0.5/0.5. out_ing = x_ing passthrough.
//
// HARNESS FACT (r0-3 forensics): float tensors are FP32 in memory.
// R4: 489us pass. R5: 381us (parallel scan). R6: k_agg was latency-bound
// (81us, 17% HBM, 34% VALU): restructured to lane-parallel softmax with
// register-held weights + shfl broadcast + unroll-4 gather; a_src fused
// into gemm (kills 51MB rowdot pass); k_prep parallelized to 129 blocks.
//
// Memory plan (all inside d_out, no d_ws dependence):
//   bytes [0, 25.6MB)      : h_ing staged as bf16 (ushort), read by k_agg
//   bytes [26MB, ~30MB)    : scratch (a_src, a_dst, CSR arrays, Wt, u, v)
//   bytes [51.2MB, 76.8MB) : out_taste (fp32, final output region 1)
//   final op: copy fp32 x_ing over bytes [0, 51.2MB) (output region 0)
// ---------------------------------------------------------------------------

typedef __attribute__((ext_vector_type(8))) short short8;   // 8 x bf16
typedef __attribute__((ext_vector_type(4))) float f32x4;

__device__ __forceinline__ float b2f(unsigned short u) {
    return __uint_as_float(((unsigned int)u) << 16);
}
__device__ __forceinline__ unsigned short f2b(float f) {
    unsigned int x = __float_as_uint(f);
    x += 0x7fffu + ((x >> 16) & 1u);   // RNE; exact for bf16-quantized values
    return (unsigned short)(x >> 16);
}

#define D 128

// --- prep (129 blocks): b<64 transpose W_ing->Wt(bf16); b>=64: 260 waves of
//     lane-parallel length-128 dots: u=W_ing@att_src, v=W_taste@att_dst,
//     cvals[0]=b_ing.att_src, cvals[1]=b_taste.att_dst
__global__ __launch_bounds__(256) void k_prep(
        const float* __restrict__ W_ing,  const float* __restrict__ b_ing,
        const float* __restrict__ W_taste,const float* __restrict__ b_taste,
        const float* __restrict__ att_src,const float* __restrict__ att_dst,
        unsigned short* __restrict__ Wt,
        float* __restrict__ u, float* __restrict__ v, float* __restrict__ cvals)
{
    int tid = threadIdx.x;
    if (blockIdx.x < 64) {                       // transpose + bf16 convert
        int idx = blockIdx.x * 256 + tid;        // 64*256 = 16384 = all elems
        int k = idx >> 7, j = idx & 127;
        Wt[j * D + k] = f2b(W_ing[idx]);
        return;
    }
    int gw = (blockIdx.x - 64) * 4 + (tid >> 6);
    int lane = tid & 63;
    const float* row; const float* vec; float* dst;
    if (gw < 128)      { row = W_ing   + (size_t)gw * D;         vec = att_src; dst = u + gw; }
    else if (gw < 256) { row = W_taste + (size_t)(gw - 128) * D; vec = att_dst; dst = v + (gw - 128); }
    else if (gw == 256){ row = b_ing;   vec = att_src; dst = cvals; }
    else if (gw == 257){ row = b_taste; vec = att_dst; dst = cvals + 1; }
    else return;
    float2 a = *(const float2*)(row + lane * 2);
    float2 w = *(const float2*)(vec + lane * 2);
    float s = a.x * w.x + a.y * w.y;
#pragma unroll
    for (int off = 32; off; off >>= 1) s += __shfl_xor(s, off);
    if (lane == 0) *dst = s;
}

// --- histogram of dst ------------------------------------------------------
__global__ __launch_bounds__(256) void k_hist(const int* __restrict__ dst,
                                              int* __restrict__ counts, int E)
{
    int e = blockIdx.x * 256 + threadIdx.x;
    if (e < E) atomicAdd(&counts[dst[e]], 1);
}

// --- 3-phase scan: A) per-block sums  B) scan sums  C) block scan + prefix -
__global__ __launch_bounds__(256) void k_scanA(const int* __restrict__ counts,
                                               int* __restrict__ blocksums, int n)
{
    __shared__ int lds[256];
    int tid = threadIdx.x;
    int i = blockIdx.x * 256 + tid;
    lds[tid] = (i < n) ? counts[i] : 0;
    __syncthreads();
#pragma unroll
    for (int off = 128; off > 0; off >>= 1) {
        if (tid < off) lds[tid] += lds[tid + off];
        __syncthreads();
    }
    if (tid == 0) blocksums[blockIdx.x] = lds[0];
}

__global__ __launch_bounds__(256) void k_scanB(const int* __restrict__ blocksums,
                                               int* __restrict__ blockpre,
                                               int* __restrict__ offsets,
                                               int nb, int n)
{
    __shared__ int lds[256];
    int tid = threadIdx.x;
    int v = (tid < nb) ? blocksums[tid] : 0;
    lds[tid] = v;
    __syncthreads();
#pragma unroll
    for (int off = 1; off < 256; off <<= 1) {
        int t = (tid >= off) ? lds[tid - off] : 0;
        __syncthreads();
        lds[tid] += t;
        __syncthreads();
    }
    if (tid < nb) blockpre[tid] = lds[tid] - v;   // exclusive prefix
    if (tid == 255) offsets[n] = lds[255];        // total
}

__global__ __launch_bounds__(256) void k_scanC(const int* __restrict__ counts,
                                               const int* __restrict__ blockpre,
                                               int* __restrict__ offsets,
                                               int* __restrict__ cursor, int n)
{
    __shared__ int lds[256];
    int tid = threadIdx.x;
    int i = blockIdx.x * 256 + tid;
    int v = (i < n) ? counts[i] : 0;
    lds[tid] = v;
    __syncthreads();
#pragma unroll
    for (int off = 1; off < 256; off <<= 1) {
        int t = (tid >= off) ? lds[tid - off] : 0;
        __syncthreads();
        lds[tid] += t;
        __syncthreads();
    }
    if (i < n) {
        int o = blockpre[blockIdx.x] + lds[tid] - v;   // exclusive
        offsets[i] = o;
        cursor[i] = o;
    }
}

// --- scatter: src indices sorted by dst ------------------------------------
__global__ __launch_bounds__(256) void k_scatter(const int* __restrict__ dst,
                                                 const int* __restrict__ srcix,
                                                 int* __restrict__ cursor,
                                                 int* __restrict__ src_sorted, int E)
{
    int e = blockIdx.x * 256 + threadIdx.x;
    if (e < E) {
        int d = dst[e];
        int pos = atomicAdd(&cursor[d], 1);
        src_sorted[pos] = srcix[e];
    }
}

// --- GEMM: H(bf16) = X(fp32) @ W + b, bf16 MFMA 16x16x32 -------------------
// block = 4 waves; wave: 32 rows x 128 cols. FUSED: a_src[row] = x.u + c0
// (fp32 dot on the already-loaded A values, quad-reduced via shfl).
__global__ __launch_bounds__(256) void k_gemm(const float* __restrict__ X,
                                              const unsigned short* __restrict__ Wt,
                                              const float* __restrict__ bvec,
                                              const float* __restrict__ u,
                                              const float* __restrict__ cvals,
                                              unsigned short* __restrict__ H,
                                              float* __restrict__ a_srcv, int M)
{
    int wave = threadIdx.x >> 6;
    int lane = threadIdx.x & 63;
    int q = lane >> 4;       // quad
    int t = lane & 15;
    long mbase = (long)blockIdx.x * 128 + wave * 32;

    f32x4 acc[2][8];
    for (int i = 0; i < 2; ++i)
        for (int j = 0; j < 8; ++j)
            acc[i][j] = (f32x4){0.f, 0.f, 0.f, 0.f};

    long r0 = mbase + t;      if (r0 >= M) r0 = M - 1;
    long r1 = mbase + 16 + t; if (r1 >= M) r1 = M - 1;
    const float* A0 = X + r0 * D;
    const float* A1 = X + r1 * D;

    float adot0 = 0.f, adot1 = 0.f;

    for (int ks = 0; ks < 4; ++ks) {
        int ko = ks * 32 + q * 8;
        float4 f0a = *(const float4*)(A0 + ko);
        float4 f0b = *(const float4*)(A0 + ko + 4);
        float4 f1a = *(const float4*)(A1 + ko);
        float4 f1b = *(const float4*)(A1 + ko + 4);
        const float* up = u + ko;
        adot0 += f0a.x*up[0] + f0a.y*up[1] + f0a.z*up[2] + f0a.w*up[3]
               + f0b.x*up[4] + f0b.y*up[5] + f0b.z*up[6] + f0b.w*up[7];
        adot1 += f1a.x*up[0] + f1a.y*up[1] + f1a.z*up[2] + f1a.w*up[3]
               + f1b.x*up[4] + f1b.y*up[5] + f1b.z*up[6] + f1b.w*up[7];
        short8 a0, a1;
        a0[0]=f2b(f0a.x); a0[1]=f2b(f0a.y); a0[2]=f2b(f0a.z); a0[3]=f2b(f0a.w);
        a0[4]=f2b(f0b.x); a0[5]=f2b(f0b.y); a0[6]=f2b(f0b.z); a0[7]=f2b(f0b.w);
        a1[0]=f2b(f1a.x); a1[1]=f2b(f1a.y); a1[2]=f2b(f1a.z); a1[3]=f2b(f1a.w);
        a1[4]=f2b(f1b.x); a1[5]=f2b(f1b.y); a1[6]=f2b(f1b.z); a1[7]=f2b(f1b.w);
#pragma unroll
        for (int nt = 0; nt < 8; ++nt) {
            short8 bfr = *(const short8*)(Wt + (nt * 16 + t) * D + ko);
            acc[0][nt] = __builtin_amdgcn_mfma_f32_16x16x32_bf16(a0, bfr, acc[0][nt], 0, 0, 0);
            acc[1][nt] = __builtin_amdgcn_mfma_f32_16x16x32_bf16(a1, bfr, acc[1][nt], 0, 0, 0);
        }
    }

    // a_src: quad-reduce (each quad holds a 32-elem k-slice of the dot)
    adot0 += __shfl_xor(adot0, 16); adot0 += __shfl_xor(adot0, 32);
    adot1 += __shfl_xor(adot1, 16); adot1 += __shfl_xor(adot1, 32);
    if (q == 0) {
        float c0 = cvals[0];
        a_srcv[r0] = adot0 + c0;     // clamped rows: duplicate same value
        a_srcv[r1] = adot1 + c0;
    }

    // C/D: col(n) = lane&15, row(m) = quad*4 + reg   [verified m89/m91]
#pragma unroll
    for (int mt = 0; mt < 2; ++mt) {
#pragma unroll
        for (int r = 0; r < 4; ++r) {
            long row = mbase + mt * 16 + q * 4 + r;
            if (row < M) {
#pragma unroll
                for (int nt = 0; nt < 8; ++nt) {
                    H[row * D + nt * 16 + t] = f2b(acc[mt][nt][r] + bvec[nt * 16 + t]);
                }
            }
        }
    }
}

// --- row dot: out[i] = x[i,:].w + c  (wave = 4 rows, 16 lanes/row) ---------
__global__ __launch_bounds__(256) void k_rowdot(const float* __restrict__ X,
                                                const float* __restrict__ w,
                                                const float* __restrict__ cptr,
                                                float* __restrict__ out, int M)
{
    int gw = (blockIdx.x * 256 + threadIdx.x) >> 6;
    int lane = threadIdx.x & 63;
    long row = (long)gw * 4 + (lane >> 4);
    int k = (lane & 15) * 8;
    float s = 0.f;
    if (row < M) {
        float4 a = *(const float4*)(X + row * D + k);
        float4 b = *(const float4*)(X + row * D + k + 4);
        s = a.x * w[k]     + a.y * w[k + 1] + a.z * w[k + 2] + a.w * w[k + 3]
          + b.x * w[k + 4] + b.y * w[k + 5] + b.z * w[k + 6] + b.w * w[k + 7];
    }
    s += __shfl_xor(s, 1);
    s += __shfl_xor(s, 2);
    s += __shfl_xor(s, 4);
    s += __shfl_xor(s, 8);
    if ((lane & 15) == 0 && row < M) out[row] = s + cptr[0];
}

// --- per-dst: segment softmax + weighted agg + relu + residual -------------
// one wave per dst. Phase A: lane-parallel over edges (lane owns edge
// start+lane; weight & src idx stay in registers). Phase B: shfl-broadcast
// per edge, unroll-4 pipelined H-row gather. deg>64 tail: rare slow path.
__global__ __launch_bounds__(256) void k_agg(const int* __restrict__ offsets,
                                             const int* __restrict__ src_sorted,
                                             const float* __restrict__ a_src,
                                             const float* __restrict__ a_dst,
                                             const unsigned short* __restrict__ H,
                                             const float* __restrict__ x_taste,
                                             float* __restrict__ out_taste,
                                             int Nt)
{
    int d = (blockIdx.x * 256 + threadIdx.x) >> 6;
    int lane = threadIdx.x & 63;
    if (d >= Nt) return;
    int start = offsets[d], end = offsets[d + 1];
    int deg = end - start;
    float ad = a_dst[d];

    // phase A: lane-parallel logits (first 64 edges held in registers)
    int mys = 0; float myl = 0.f;
    bool has = (start + lane < end);
    if (has) {
        mys = src_sorted[start + lane];
        float l = a_src[mys] + ad;
        myl = l > 0.f ? l : 0.2f * l;
    }
    float m = has ? myl : -3.4e38f;
    for (int base = start + 64; base < end; base += 64) {   // rare
        int e = base + lane;
        if (e < end) {
            float l = a_src[src_sorted[e]] + ad;
            l = l > 0.f ? l : 0.2f * l;
            m = fmaxf(m, l);
        }
    }
#pragma unroll
    for (int off = 32; off; off >>= 1) m = fmaxf(m, __shfl_xor(m, off));

    float ssum = has ? __expf(myl - m) : 0.f;
    for (int base = start + 64; base < end; base += 64) {   // rare
        int e = base + lane;
        if (e < end) {
            float l = a_src[src_sorted[e]] + ad;
            l = l > 0.f ? l : 0.2f * l;
            ssum += __expf(l - m);
        }
    }
#pragma unroll
    for (int off = 32; off; off >>= 1) ssum += __shfl_xor(ssum, off);
    float inv = 1.0f / (ssum + 1e-16f);
    float myw = has ? __expf(myl - m) * inv : 0.f;

    // phase B: broadcast weights/indices from registers, gather H rows
    float acc0 = 0.f, acc1 = 0.f;
    int dfirst = deg < 64 ? deg : 64;
    int i = 0;
    for (; i + 4 <= dfirst; i += 4) {
        int s0 = __shfl(mys, i),     s1 = __shfl(mys, i + 1);
        int s2 = __shfl(mys, i + 2), s3 = __shfl(mys, i + 3);
        float w0 = __shfl(myw, i),     w1 = __shfl(myw, i + 1);
        float w2 = __shfl(myw, i + 2), w3 = __shfl(myw, i + 3);
        unsigned int h0 = *(const unsigned int*)(H + (long)s0 * D + lane * 2);
        unsigned int h1 = *(const unsigned int*)(H + (long)s1 * D + lane * 2);
        unsigned int h2 = *(const unsigned int*)(H + (long)s2 * D + lane * 2);
        unsigned int h3 = *(const unsigned int*)(H + (long)s3 * D + lane * 2);
        acc0 += w0 * b2f((unsigned short)(h0 & 0xffffu)) + w1 * b2f((unsigned short)(h1 & 0xffffu))
              + w2 * b2f((unsigned short)(h2 & 0xffffu)) + w3 * b2f((unsigned short)(h3 & 0xffffu));
        acc1 += w0 * b2f((unsigned short)(h0 >> 16)) + w1 * b2f((unsigned short)(h1 >> 16))
              + w2 * b2f((unsigned short)(h2 >> 16)) + w3 * b2f((unsigned short)(h3 >> 16));
    }
    for (; i < dfirst; ++i) {
        int s0 = __shfl(mys, i);
        float w0 = __shfl(myw, i);
        unsigned int h0 = *(const unsigned int*)(H + (long)s0 * D + lane * 2);
        acc0 += w0 * b2f((unsigned short)(h0 & 0xffffu));
        acc1 += w0 * b2f((unsigned short)(h0 >> 16));
    }
    for (int e = start + 64; e < end; ++e) {                // rare tail
        int s = src_sorted[e];
        float l = a_src[s] + ad;
        l = l > 0.f ? l : 0.2f * l;
        float w = __expf(l - m) * inv;
        unsigned int hv = *(const unsigned int*)(H + (long)s * D + lane * 2);
        acc0 += w * b2f((unsigned short)(hv & 0xffffu));
        acc1 += w * b2f((unsigned short)(hv >> 16));
    }

    float2 xv = *(const float2*)(x_taste + (long)d * D + lane * 2);
    float2 ov;
    ov.x = 0.5f * (fmaxf(acc0, 0.f) + xv.x);
    ov.y = 0.5f * (fmaxf(acc1, 0.f) + xv.y);
    *(float2*)(out_taste + (long)d * D + lane * 2) = ov;
}

// --- passthrough copy: out_ing = x_ing (16B/thread, grid-stride) -----------
__global__ __launch_bounds__(256) void k_copy(const uint4* __restrict__ src,
                                              uint4* __restrict__ dst, long n16)
{
    long i = (long)blockIdx.x * 256 + threadIdx.x;
    long stride = (long)gridDim.x * 256;
    for (; i < n16; i += stride) dst[i] = src[i];
}

extern "C" void kernel_launch(void* const* d_in, const int* in_sizes, int n_in,
                              void* d_out, int out_size, void* d_ws, size_t ws_size,
                              hipStream_t stream)
{
    const float* x_ing   = (const float*)d_in[0];
    const float* x_taste = (const float*)d_in[1];
    const float* W_ing   = (const float*)d_in[2];
    const float* b_ing   = (const float*)d_in[3];
    const float* W_taste = (const float*)d_in[4];
    const float* b_taste = (const float*)d_in[5];
    const float* att_src = (const float*)d_in[6];
    const float* att_dst = (const float*)d_in[7];
    // d_in[8..10] = Wk, bk, q: dead (softmax over single metapath == 1.0)
    const int* src_idx = (const int*)d_in[11];
    const int* dst_idx = (const int*)d_in[12];

    const int NI = in_sizes[0] / D;   // 100000
    const int NT = in_sizes[1] / D;   // 50000
    const int E  = in_sizes[11];      // 600000

    float* out = (float*)d_out;
    float* out_taste = out + (size_t)NI * D;               // region 1 (fp32)
    unsigned short* h_ing = (unsigned short*)d_out;        // bytes [0,25.6MB)

    // scratch inside d_out at byte offset 26MB (wiped by final x_ing copy)
    char* ws = (char*)d_out + (size_t)26 * 1024 * 1024;
    size_t off = 0;
    auto alloc = [&](size_t bytes) -> void* {
        void* p = ws + off;
        off = (off + bytes + 255) & ~(size_t)255;
        return p;
    };
    float* a_src     = (float*)alloc((size_t)NI * 4);
    float* a_dst     = (float*)alloc((size_t)NT * 4);
    int* counts      = (int*)alloc((size_t)NT * 4);
    int* cursor      = (int*)alloc((size_t)NT * 4);
    int* offsets     = (int*)alloc((size_t)(NT + 1) * 4);
    int* src_sorted  = (int*)alloc((size_t)E * 4);
    unsigned short* Wt = (unsigned short*)alloc((size_t)D * D * 2);
    float* u         = (float*)alloc(D * 4);
    float* v         = (float*)alloc(D * 4);
    float* cvals     = (float*)alloc(2 * 4);
    int* blocksums   = (int*)alloc(256 * 4);
    int* blockpre    = (int*)alloc(256 * 4);
    (void)d_ws; (void)ws_size;

    const int nb = (NT + 255) / 256;   // 196 scan blocks

    hipMemsetAsync(counts, 0, (size_t)NT * 4, stream);

    k_prep<<<129, 256, 0, stream>>>(W_ing, b_ing, W_taste, b_taste,
                                    att_src, att_dst, Wt, u, v, cvals);

    k_hist<<<(E + 255) / 256, 256, 0, stream>>>(dst_idx, counts, E);
    k_scanA<<<nb, 256, 0, stream>>>(counts, blocksums, NT);
    k_scanB<<<1, 256, 0, stream>>>(blocksums, blockpre, offsets, nb, NT);
    k_scanC<<<nb, 256, 0, stream>>>(counts, blockpre, offsets, cursor, NT);
    k_scatter<<<(E + 255) / 256, 256, 0, stream>>>(dst_idx, src_idx, cursor, src_sorted, E);

    // gemm fuses a_src = x_ing.(W_ing att_src) + b_ing.att_src
    k_gemm<<<(NI + 127) / 128, 256, 0, stream>>>(x_ing, Wt, b_ing, u, cvals,
                                                 h_ing, a_src, NI);

    // a_dst = x_taste @ (W_taste @ att_dst) + b_taste.att_dst
    k_rowdot<<<((NT + 3) / 4 * 64 + 255) / 256, 256, 0, stream>>>(x_taste, v, cvals + 1, a_dst, NT);

    k_agg<<<(NT * 64 + 255) / 256, 256, 0, stream>>>(offsets, src_sorted, a_src, a_dst,
                                                     h_ing, x_taste, out_taste, NT);

    // out_ing = x_ing passthrough — LAST op, wipes h_ing staging + scratch
    long n16 = ((long)NI * D * 4) / 16;
    k_copy<<<2048, 256, 0, stream>>>((const uint4*)x_ing, (uint4*)out, n16);
}